// Round 5
// baseline (319.100 us; speedup 1.0000x reference)
//
#include <hip/hip_runtime.h>

#define B_ROWS 16384
#define FEAT   2048
#define MARGIN 1.0f

typedef float vfloat4 __attribute__((ext_vector_type(4)));

// Stage 1: one block (256 thr) per 2 rows; each half-block (128 thr, 2 waves)
// owns one row; 4 float4 per thread per stream = 12 independent loads.
__global__ __launch_bounds__(256) void TripletLoss_90091234001212_kernel(
    const float* __restrict__ anc,
    const float* __restrict__ pos,
    const float* __restrict__ neg,
    float* __restrict__ ws)
{
    const int tid    = threadIdx.x;
    const int lane   = tid & 63;
    const int wave   = tid >> 6;          // 0..3
    const int tid128 = tid & 127;
    const int rloc   = tid >> 7;          // 0..1
    const int row    = blockIdx.x * 2 + rloc;

    const vfloat4* a4 = (const vfloat4*)(anc + (size_t)row * FEAT);
    const vfloat4* p4 = (const vfloat4*)(pos + (size_t)row * FEAT);
    const vfloat4* n4 = (const vfloat4*)(neg + (size_t)row * FEAT);

    // 512 float4 per row / 128 threads = 4 per thread per stream.
    const int i0 = tid128;
    const int i1 = tid128 + 128;
    const int i2 = tid128 + 256;
    const int i3 = tid128 + 384;
    const vfloat4 a0 = __builtin_nontemporal_load(&a4[i0]);
    const vfloat4 a1 = __builtin_nontemporal_load(&a4[i1]);
    const vfloat4 a2 = __builtin_nontemporal_load(&a4[i2]);
    const vfloat4 a3 = __builtin_nontemporal_load(&a4[i3]);
    const vfloat4 p0 = __builtin_nontemporal_load(&p4[i0]);
    const vfloat4 p1 = __builtin_nontemporal_load(&p4[i1]);
    const vfloat4 p2 = __builtin_nontemporal_load(&p4[i2]);
    const vfloat4 p3 = __builtin_nontemporal_load(&p4[i3]);
    const vfloat4 n0 = __builtin_nontemporal_load(&n4[i0]);
    const vfloat4 n1 = __builtin_nontemporal_load(&n4[i1]);
    const vfloat4 n2 = __builtin_nontemporal_load(&n4[i2]);
    const vfloat4 n3 = __builtin_nontemporal_load(&n4[i3]);

    float dp = 0.0f, dn = 0.0f;
    {
        vfloat4 d;
        d = a0 - p0; dp += d.x*d.x + d.y*d.y + d.z*d.z + d.w*d.w;
        d = a1 - p1; dp += d.x*d.x + d.y*d.y + d.z*d.z + d.w*d.w;
        d = a2 - p2; dp += d.x*d.x + d.y*d.y + d.z*d.z + d.w*d.w;
        d = a3 - p3; dp += d.x*d.x + d.y*d.y + d.z*d.z + d.w*d.w;
        d = a0 - n0; dn += d.x*d.x + d.y*d.y + d.z*d.z + d.w*d.w;
        d = a1 - n1; dn += d.x*d.x + d.y*d.y + d.z*d.z + d.w*d.w;
        d = a2 - n2; dn += d.x*d.x + d.y*d.y + d.z*d.z + d.w*d.w;
        d = a3 - n3; dn += d.x*d.x + d.y*d.y + d.z*d.z + d.w*d.w;
    }

    // wave-64 butterfly reduce (two values)
    #pragma unroll
    for (int off = 32; off > 0; off >>= 1) {
        dp += __shfl_down(dp, off);
        dn += __shfl_down(dn, off);
    }

    __shared__ float sdp[4], sdn[4];
    if (lane == 0) { sdp[wave] = dp; sdn[wave] = dn; }
    __syncthreads();

    // one writer per row (tid 0 -> row 0 via waves 0,1; tid 128 -> row 1 via waves 2,3)
    if (lane == 0 && (wave & 1) == 0) {
        const int w0 = wave;          // 0 or 2
        const float tdp = sdp[w0] + sdp[w0 + 1];
        const float tdn = sdn[w0] + sdn[w0 + 1];
        const float loss = sqrtf(tdp) - sqrtf(tdn) + MARGIN;
        ws[row] = fmaxf(loss, 0.0f);
    }
}

// Stage 2: reduce B_ROWS partials -> out[0]
__global__ __launch_bounds__(256) void tl_reduce(
    const float* __restrict__ ws, float* __restrict__ out)
{
    const int tid  = threadIdx.x;
    const int lane = tid & 63;
    const int wave = tid >> 6;

    // 16384 floats = 4096 float4; 256 threads x 16 float4
    const vfloat4* w4 = (const vfloat4*)ws;
    float s = 0.0f;
    #pragma unroll
    for (int it = 0; it < 16; ++it) {
        const vfloat4 v = w4[it * 256 + tid];
        s += v.x + v.y + v.z + v.w;
    }

    #pragma unroll
    for (int off = 32; off > 0; off >>= 1) {
        s += __shfl_down(s, off);
    }

    __shared__ float partial[4];
    if (lane == 0) partial[wave] = s;
    __syncthreads();

    if (tid == 0) {
        out[0] = (partial[0] + partial[1] + partial[2] + partial[3])
                 * (1.0f / (float)B_ROWS);
    }
}

extern "C" void kernel_launch(void* const* d_in, const int* in_sizes, int n_in,
                              void* d_out, int out_size, void* d_ws, size_t ws_size,
                              hipStream_t stream) {
    const float* anc = (const float*)d_in[0];
    const float* pos = (const float*)d_in[1];
    const float* neg = (const float*)d_in[2];
    float* out = (float*)d_out;
    float* ws  = (float*)d_ws;

    TripletLoss_90091234001212_kernel<<<B_ROWS / 2, 256, 0, stream>>>(anc, pos, neg, ws);
    tl_reduce<<<1, 256, 0, stream>>>(ws, out);
}